// Round 8
// baseline (273.707 us; speedup 1.0000x reference)
//
#include <hip/hip_runtime.h>
#include <math.h>

#define NN 50000
#define NNP 50176            // padded rows (block tail writes unguarded)
#define NE 600000
#define NG 64
#define INCH 768
#define HID 128

typedef __attribute__((ext_vector_type(8))) short bf16x8;
typedef __attribute__((ext_vector_type(4))) float f32x4;
typedef __attribute__((ext_vector_type(4))) unsigned int u32x4;
typedef unsigned short u16;
typedef unsigned int u32;
typedef unsigned long long u64;

__device__ __forceinline__ u16 f2bf(float v) {
    u32 u = __builtin_bit_cast(u32, v);
    u32 r = u + 0x7FFFu + ((u >> 16) & 1u);
    return (u16)(r >> 16);
}
__device__ __forceinline__ float bf2f(u16 h) {
    u32 u = ((u32)h) << 16;
    return __builtin_bit_cast(float, u);
}
__device__ __forceinline__ u32 cvtpk(float a, float b) {
    u32 r;
    asm("v_cvt_pk_bf16_f32 %0, %1, %2" : "=v"(r) : "v"(a), "v"(b));
    return r;
}
// async global->LDS, 16B per lane (dest = wave-uniform base + lane*16)
__device__ __forceinline__ void gl_lds16(const void* g, void* l) {
    __builtin_amdgcn_global_load_lds(
        (const __attribute__((address_space(1))) unsigned int*)g,
        (__attribute__((address_space(3))) unsigned int*)l, 16, 0, 0);
}

struct SplitA { bf16x8 h, l; };

template <bool RELU>
__device__ __forceinline__ SplitA splitA(float4 b0, float4 b1) {
    if (RELU) {
        b0.x = fmaxf(b0.x, 0.f); b0.y = fmaxf(b0.y, 0.f);
        b0.z = fmaxf(b0.z, 0.f); b0.w = fmaxf(b0.w, 0.f);
        b1.x = fmaxf(b1.x, 0.f); b1.y = fmaxf(b1.y, 0.f);
        b1.z = fmaxf(b1.z, 0.f); b1.w = fmaxf(b1.w, 0.f);
    }
    u32 h0 = cvtpk(b0.x, b0.y), h1 = cvtpk(b0.z, b0.w);
    u32 h2 = cvtpk(b1.x, b1.y), h3 = cvtpk(b1.z, b1.w);
    float r0 = b0.x - __builtin_bit_cast(float, h0 << 16);
    float r1 = b0.y - __builtin_bit_cast(float, h0 & 0xFFFF0000u);
    float r2 = b0.z - __builtin_bit_cast(float, h1 << 16);
    float r3 = b0.w - __builtin_bit_cast(float, h1 & 0xFFFF0000u);
    float r4 = b1.x - __builtin_bit_cast(float, h2 << 16);
    float r5 = b1.y - __builtin_bit_cast(float, h2 & 0xFFFF0000u);
    float r6 = b1.z - __builtin_bit_cast(float, h3 << 16);
    float r7 = b1.w - __builtin_bit_cast(float, h3 & 0xFFFF0000u);
    u32 e0 = cvtpk(r0, r1), e1 = cvtpk(r2, r3);
    u32 e2 = cvtpk(r4, r5), e3 = cvtpk(r6, r7);
    SplitA s;
    s.h = __builtin_bit_cast(bf16x8, (u32x4){h0, h1, h2, h3});
    s.l = __builtin_bit_cast(bf16x8, (u32x4){e0, e1, e2, e3});
    return s;
}

// elementwise relu on 8 packed bf16 (exact: relu(bf16(x)) == bf16(relu(x)))
__device__ __forceinline__ bf16x8 relu8(bf16x8 a) {
    u32x4 u = __builtin_bit_cast(u32x4, a);
#pragma unroll
    for (int i = 0; i < 4; i++) {
        u32 x = u[i];
        u32 lo = (x & 0x8000u) ? 0u : (x & 0x0000FFFFu);
        u32 hi = (x & 0x80000000u) ? 0u : (x & 0xFFFF0000u);
        u[i] = lo | hi;
    }
    return __builtin_bit_cast(bf16x8, u);
}

// ---------------------------------------------------------------------------
__global__ void deg_count(const int* __restrict__ dst, int* counts) {
    int e = blockIdx.x * blockDim.x + threadIdx.x;
    if (e < NE) atomicAdd(&counts[dst[e]], 1);
}

// ---------------------------------------------------------------------------
// CSR build (pscan1 also emits dinv = rsqrt(deg+1))
// ---------------------------------------------------------------------------
__global__ void pscan1(const int* __restrict__ counts, int* __restrict__ row_start,
                       int* __restrict__ bsum, float* __restrict__ dinv) {
    __shared__ int sm[256];
    int t = threadIdx.x;
    int i = blockIdx.x * 256 + t;
    int v = (i < NN) ? counts[i] : 0;
    if (i < NN) dinv[i] = rsqrtf((float)v + 1.0f);
    sm[t] = v;
    __syncthreads();
#pragma unroll
    for (int off = 1; off < 256; off <<= 1) {
        int add = (t >= off) ? sm[t - off] : 0;
        __syncthreads();
        sm[t] += add;
        __syncthreads();
    }
    row_start[i] = sm[t] - v;
    if (t == 255) bsum[blockIdx.x] = sm[t];
}

__global__ void pscan2(int* bsum, int nb) {
    __shared__ int sm[256];
    int t = threadIdx.x;
    int v = (t < nb) ? bsum[t] : 0;
    sm[t] = v;
    __syncthreads();
#pragma unroll
    for (int off = 1; off < 256; off <<= 1) {
        int add = (t >= off) ? sm[t - off] : 0;
        __syncthreads();
        sm[t] += add;
        __syncthreads();
    }
    if (t < nb) bsum[t] = sm[t] - v;
}

__global__ void pscan3(int* __restrict__ row_start, const int* __restrict__ bsum,
                       int* __restrict__ cursor) {
    int i = blockIdx.x * 256 + threadIdx.x;
    int v = row_start[i] + bsum[blockIdx.x];
    row_start[i] = v;
    if (i < NN) cursor[i] = v;
}

__global__ void csr_fill(const int* __restrict__ src, const int* __restrict__ dst,
                         int* __restrict__ cursor, int* __restrict__ csr_src) {
    int e = blockIdx.x * blockDim.x + threadIdx.x;
    if (e < NE) {
        int pos = atomicAdd(&cursor[dst[e]], 1);
        csr_src[pos] = src[e];
    }
}

// ---------------------------------------------------------------------------
// condW[g][c] = substring_embed[g] @ W1[768: , c]  (512 thr, 4-way K split)
// ---------------------------------------------------------------------------
__global__ __launch_bounds__(512)
void cond_gemm(const float* __restrict__ SE, const float* __restrict__ W1,
               float* __restrict__ condW) {
    __shared__ float se[INCH];
    __shared__ float part[4][HID];
    int g = blockIdx.x, t = threadIdx.x;
    for (int i = t; i < INCH; i += 512) se[i] = SE[g * INCH + i];
    __syncthreads();
    int col = t & 127, ks = t >> 7;
    const float* Wb = W1 + (size_t)INCH * HID;
    float acc = 0.f;
    for (int k = ks * 192; k < ks * 192 + 192; k++)
        acc = fmaf(se[k], Wb[(size_t)k * HID + col], acc);
    part[ks][col] = acc;
    __syncthreads();
    if (t < HID)
        condW[g * HID + t] = part[0][t] + part[1][t] + part[2][t] + part[3][t];
}

// ---------------------------------------------------------------------------
// Pack W [K][128] fp32 into MFMA fragment order, hi/lo bf16.
// chunk c (16KB): bh at [0,8K) as [f][lane][8e], bl at [8K,16K)
// ---------------------------------------------------------------------------
__global__ void wt_pack(const float* __restrict__ W, u16* __restrict__ P, int K) {
    int tid = blockIdx.x * blockDim.x + threadIdx.x;
    int total = (K / 32) * 512;
    if (tid >= total) return;
    int l = tid & 63;
    int f = (tid >> 6) & 7;
    int c = tid >> 9;
    int n = f * 16 + (l & 15);
    int kb = c * 32 + ((l >> 4) & 3) * 8;
    u64 h0 = 0, h1 = 0, l0 = 0, l1 = 0;
#pragma unroll
    for (int e = 0; e < 8; e++) {
        float v = W[(size_t)(kb + e) * HID + n];
        u16 h = f2bf(v);
        u16 r = f2bf(v - bf2f(h));
        if (e < 4) { h0 |= (u64)h << (16 * e);       l0 |= (u64)r << (16 * e); }
        else       { h1 |= (u64)h << (16 * (e - 4)); l1 |= (u64)r << (16 * (e - 4)); }
    }
    size_t base = (size_t)c * 8192 + (size_t)f * 512 + l * 8;
    *(u64*)&P[base]          = h0;
    *(u64*)&P[base + 4]      = h1;
    *(u64*)&P[base + 4096]   = l0;
    *(u64*)&P[base + 4100]   = l1;
}

// ---------------------------------------------------------------------------
// Cbf[M,128] (bf16) = (op(A) @ W + cond) * dinv[row]
// BM=64 (16 rows/wave, grid 782 -> ~3 blocks/CU). B chunk (16KB) staged to
// LDS via async global_load_lds, double-buffered, one barrier per chunk.
// ABF16: A is exact bf16 -> 2-term MFMA (A*Wh + A*Wl); else split-3.
// ---------------------------------------------------------------------------
template <int K, bool ABF16, bool RELU_A, bool ADD_COND>
__global__ __launch_bounds__(256, 3)
void mfma_gemm(const void* __restrict__ Av, const u16* __restrict__ P,
               u16* __restrict__ Cbf, const float* __restrict__ condW,
               const int* __restrict__ batch, const float* __restrict__ dinv,
               int M) {
    constexpr int NC = K / 32;
    __shared__ u16 smem[16384];   // 2 x 16KB B buffers; epilogue reuses [0,8448)
    const int t = threadIdx.x;
    const int w = t >> 6;
    const int l = t & 63;
    const int l16 = l & 15;
    const int lq = l >> 4;
    const int m0 = blockIdx.x * 64;

    const int r0 = m0 + w * 16 + l16;
    const bool ok0 = r0 < M;
    const float* Apf = (const float*)Av + (size_t)(ok0 ? r0 : 0) * K + lq * 8;
    const u16*   Apb = (const u16*)Av + (size_t)(ok0 ? r0 : 0) * K + lq * 8;
    const char* Pbase = (const char*)P;

    f32x4 acc[8] = {};

    // ---- prologue: async-stage chunk 0, load A chunk 0 ----
    {
        const char* src = Pbase + t * 16;
        char* d = (char*)smem + t * 16;
        gl_lds16(src,         d);
        gl_lds16(src + 4096,  d + 4096);
        gl_lds16(src + 8192,  d + 8192);
        gl_lds16(src + 12288, d + 12288);
    }
    float4 a0 = make_float4(0.f, 0.f, 0.f, 0.f), a1 = a0;
    bf16x8 ab = {};
    if constexpr (ABF16) {
        if (ok0) ab = *(const bf16x8*)Apb;
    } else {
        if (ok0) { a0 = *(const float4*)Apf; a1 = *(const float4*)(Apf + 4); }
    }
    __syncthreads();   // drains the DMA (vmcnt) + all waves ready

    for (int c = 0; c < NC; ++c) {
        const int cur = (c & 1) * 8192;   // u16 units
        const int nxt = cur ^ 8192;
        const bool hasNext = (c + 1 < NC);

        // (1) issue next-chunk DMA + next-A loads (complete under compute)
        float4 n0 = a0, n1 = a1;
        bf16x8 nb = ab;
        if (hasNext) {
            const char* src = Pbase + (size_t)(c + 1) * 16384 + t * 16;
            char* d = (char*)smem + nxt * 2 + t * 16;
            gl_lds16(src,         d);
            gl_lds16(src + 4096,  d + 4096);
            gl_lds16(src + 8192,  d + 8192);
            gl_lds16(src + 12288, d + 12288);
            if constexpr (ABF16) {
                if (ok0) nb = *(const bf16x8*)(Apb + 32 * (c + 1));
            } else {
                if (ok0) {
                    n0 = *(const float4*)(Apf + 32 * (c + 1));
                    n1 = *(const float4*)(Apf + 32 * (c + 1) + 4);
                }
            }
        }

        // (2) B fragments from LDS (linear, conflict-free)
        bf16x8 bh[8], bl[8];
#pragma unroll
        for (int f = 0; f < 8; f++)
            bh[f] = *(const bf16x8*)&smem[cur + f * 512 + l * 8];
#pragma unroll
        for (int f = 0; f < 8; f++)
            bl[f] = *(const bf16x8*)&smem[cur + 4096 + f * 512 + l * 8];

        // (3) MFMAs
        if constexpr (ABF16) {
            bf16x8 ah = RELU_A ? relu8(ab) : ab;
#pragma unroll
            for (int f = 0; f < 8; f++)
                acc[f] = __builtin_amdgcn_mfma_f32_16x16x32_bf16(ah, bh[f], acc[f], 0, 0, 0);
#pragma unroll
            for (int f = 0; f < 8; f++)
                acc[f] = __builtin_amdgcn_mfma_f32_16x16x32_bf16(ah, bl[f], acc[f], 0, 0, 0);
        } else {
            SplitA s0 = splitA<RELU_A>(a0, a1);
#pragma unroll
            for (int f = 0; f < 8; f++)
                acc[f] = __builtin_amdgcn_mfma_f32_16x16x32_bf16(s0.h, bh[f], acc[f], 0, 0, 0);
#pragma unroll
            for (int f = 0; f < 8; f++)
                acc[f] = __builtin_amdgcn_mfma_f32_16x16x32_bf16(s0.l, bh[f], acc[f], 0, 0, 0);
#pragma unroll
            for (int f = 0; f < 8; f++)
                acc[f] = __builtin_amdgcn_mfma_f32_16x16x32_bf16(s0.h, bl[f], acc[f], 0, 0, 0);
        }

        // (4) rotate A; barrier waits DMA (vmcnt) + frees cur for overwrite
        a0 = n0; a1 = n1; ab = nb;
        __syncthreads();
    }

    // ---- epilogue: scale+cond, pack bf16 via per-wave LDS slice ----
    u16* lds = smem + w * 2112;   // 16 rows x 132 u16
#pragma unroll
    for (int j = 0; j < 4; j++) {
        int rl = lq * 4 + j;
        int grow = m0 + w * 16 + rl;
        int gs = grow < M ? grow : M - 1;
        float scale = dinv[gs];
        int gb = 0;
        if (ADD_COND) gb = batch[gs];
#pragma unroll
        for (int f = 0; f < 8; f++) {
            float v = acc[f][j];
            if (ADD_COND) v += condW[gb * HID + f * 16 + l16];
            lds[rl * 132 + f * 16 + l16] = f2bf(v * scale);
        }
    }
#pragma unroll
    for (int pass = 0; pass < 4; pass++) {
        int row = pass * 4 + lq;
        bf16x8 v = *(const bf16x8*)&lds[row * 132 + l16 * 8];
        *(bf16x8*)&Cbf[(size_t)(m0 + w * 16 + row) * HID + l16 * 8] = v;
    }
}

// ---------------------------------------------------------------------------
// gather aggregation over packed-bf16 u:
//   o[d] = bias + dinv[d]*(u[d] + sum u[src])
// MODE 0: write o as packed bf16 (u32/lane).  MODE 1: fused output head.
// ---------------------------------------------------------------------------
template <int MODE>
__global__ __launch_bounds__(256)
void agg_gather(const u32* __restrict__ u, const float* __restrict__ dinv,
                const int* __restrict__ row_start, const int* __restrict__ csr_src,
                const float* __restrict__ bias, u32* __restrict__ outbf,
                const float* __restrict__ Wout, const float* __restrict__ bout,
                float* __restrict__ logits) {
    int node = blockIdx.x * 4 + (threadIdx.x >> 6);
    int lane = threadIdx.x & 63;
    if (node >= NN) return;
    int p = row_start[node], pend = row_start[node + 1];
    u32 pv = u[(size_t)node * 64 + lane];
    float ax = __builtin_bit_cast(float, pv << 16);
    float ay = __builtin_bit_cast(float, pv & 0xFFFF0000u);
    int s = (p < pend) ? csr_src[p] : 0;
    while (p < pend) {
        int sn = (p + 1 < pend) ? csr_src[p + 1] : 0;
        u32 v = u[(size_t)s * 64 + lane];
        ax += __builtin_bit_cast(float, v << 16);
        ay += __builtin_bit_cast(float, v & 0xFFFF0000u);
        s = sn;
        ++p;
    }
    float dd = dinv[node];
    float2 bb = *(const float2*)&bias[lane * 2];
    float ox = fmaf(dd, ax, bb.x);
    float oy = fmaf(dd, ay, bb.y);
    if (MODE == 1) {
        float2 wv = *(const float2*)&Wout[lane * 2];
        float v = fmaxf(ox, 0.f) * wv.x + fmaxf(oy, 0.f) * wv.y;
#pragma unroll
        for (int o = 32; o; o >>= 1) v += __shfl_down(v, o);
        if (lane == 0) logits[node] = v + bout[0];
    } else {
        outbf[(size_t)node * 64 + lane] = cvtpk(ox, oy);
    }
}

// ---------------------------------------------------------------------------
extern "C" void kernel_launch(void* const* d_in, const int* in_sizes, int n_in,
                              void* d_out, int out_size, void* d_ws, size_t ws_size,
                              hipStream_t stream) {
    const float* x     = (const float*)d_in[0];
    const int*   ei    = (const int*)d_in[1];
    const float* se    = (const float*)d_in[2];
    const int*   batch = (const int*)d_in[3];
    const float* W1    = (const float*)d_in[4];
    const float* b1    = (const float*)d_in[5];
    const float* W2    = (const float*)d_in[6];
    const float* b2    = (const float*)d_in[7];
    const float* Wout  = (const float*)d_in[8];
    const float* bout  = (const float*)d_in[9];
    float* logits = (float*)d_out;

    const int* srcp = ei;
    const int* dstp = ei + NE;

    // workspace carve (float offsets; 16B-aligned)
    float* ws       = (float*)d_ws;
    float* dinv     = ws;                        // 50176
    float* condW    = ws + 50176;                // 8192
    u16*   W1p      = (u16*)(ws + 58368);        // 98304 f
    u16*   W2p      = (u16*)(ws + 156672);       // 16384 f
    int*   counts   = (int*)(ws + 173056);       // 50176 (reused as cursor)
    int*   row_st   = (int*)(ws + 223232);       // 50176
    int*   csr_src  = (int*)(ws + 273408);       // 600000
    int*   bsum     = (int*)(ws + 873408);       // 256
    float* bufA     = ws + 873664;               // NNP*128 f region

    u16* ubf  = (u16*)bufA;                      // u (bf16), both layers
    u16* h1bf = (u16*)(bufA + (size_t)NNP * 64); // h1 (bf16)

    const int NB = (NN + 255) / 256;  // 196

    // degree + CSR build
    hipMemsetAsync(counts, 0, NN * sizeof(int), stream);
    deg_count<<<(NE + 255) / 256, 256, 0, stream>>>(dstp, counts);
    pscan1<<<NB, 256, 0, stream>>>(counts, row_st, bsum, dinv);
    pscan2<<<1, 256, 0, stream>>>(bsum, NB);
    pscan3<<<NB, 256, 0, stream>>>(row_st, bsum, counts);
    csr_fill<<<(NE + 255) / 256, 256, 0, stream>>>(srcp, dstp, counts, csr_src);

    // weight prep
    cond_gemm<<<NG, 512, 0, stream>>>(se, W1, condW);
    wt_pack<<<(24 * 512 + 255) / 256, 256, 0, stream>>>(W1, W1p, INCH);
    wt_pack<<<(4 * 512 + 255) / 256, 256, 0, stream>>>(W2, W2p, HID);

    const int GB = (NN + 63) / 64;   // 782

    // layer 1: u1(bf16) = (x @ W1[:768] + condW[batch]) * dinv
    mfma_gemm<INCH, false, false, true><<<GB, 256, 0, stream>>>(
        x, W1p, ubf, condW, batch, dinv, NN);
    agg_gather<0><<<(NN + 3) / 4, 256, 0, stream>>>(
        (const u32*)ubf, dinv, row_st, csr_src, b1, (u32*)h1bf,
        nullptr, nullptr, nullptr);

    // layer 2: u2(bf16) = (relu(h1bf) @ W2) * dinv ; gather + fused head
    mfma_gemm<HID, true, true, false><<<GB, 256, 0, stream>>>(
        h1bf, W2p, ubf, nullptr, nullptr, dinv, NN);
    agg_gather<1><<<(NN + 3) / 4, 256, 0, stream>>>(
        (const u32*)ubf, dinv, row_st, csr_src, b2, nullptr, Wout, bout, logits);
}